// Round 9
// baseline (693.649 us; speedup 1.0000x reference)
//
#include <hip/hip_runtime.h>
#include <hip/hip_bf16.h>

// SeqExperts: 64 experts, 128 tokens each, d_model=1024, d_hidden=4096.
// out[e*128+m] = relu(x_e @ W1[e]^T) @ W2[e]^T
// R3 (540): counted-vmcnt double-buffer, XCD swizzle, BK=32, 128x128 tile.
// R4 (794 FAIL) no-LDS. R5 (707 FAIL) broken coalescing. R6 (521, BEST):
// BK=64 + chunk-XOR swizzle + pack2 + nontemporal W + x->bf16 prepass.
// R7 (529): depth-3 flat. R8 (622 FAIL): 128x64 tile / 4 blk/CU.
// R9: SINGLE persistent dispatch: pass1 (blocks 0..2047) + pass2 (2048..2559)
//     with per-expert atomic gating (release/acquire, agent scope).
//     Removes the inter-pass dispatch boundary, overlaps pass2's W2 stream
//     with pass1's drain tail, kills pass2's single-generation quantization.
//     GEMM internals identical to R6.

typedef __attribute__((ext_vector_type(8))) short bf16x8;   // 8 bf16 (4 VGPRs)
typedef __attribute__((ext_vector_type(4))) float f32x4;
typedef __attribute__((ext_vector_type(4))) unsigned int u32x4;

#define N_EXPERTS 64
#define DM 1024
#define DH 4096
#define TOKS 128

__device__ __forceinline__ unsigned f2u(float f) {
    union { float f; unsigned u; } v; v.f = f; return v.u;
}
// round-half-up fp32->bf16 (0.5 ulp; no NaN/inf in data)
__device__ __forceinline__ unsigned short f2bf(float f) {
    return (unsigned short)((f2u(f) + 0x8000u) >> 16);
}
// pack two fp32 -> 2xbf16 in one u32
__device__ __forceinline__ unsigned pack2(float lo, float hi) {
    return ((f2u(lo) + 0x8000u) >> 16) | ((f2u(hi) + 0x8000u) & 0xFFFF0000u);
}

// elementwise fp32 -> bf16 (8 elems/thread) + zero the 64 expert gate counters
__global__ __launch_bounds__(256)
void cvt_bf16(const float* __restrict__ in, unsigned* __restrict__ outp, int n8,
              int* __restrict__ cnt) {
    int i = blockIdx.x * blockDim.x + threadIdx.x;
    if (blockIdx.x == 0 && threadIdx.x < N_EXPERTS) cnt[threadIdx.x] = 0;
    if (i >= n8) return;
    const f32x4* p = (const f32x4*)in + (size_t)i * 2;
    f32x4 a = p[0], b = p[1];
    u32x4 o = { pack2(a[0], a[1]), pack2(a[2], a[3]),
                pack2(b[0], b[1]), pack2(b[2], b[3]) };
    *((u32x4*)outp + i) = o;
}

// One 128xN-tile GEMM: C[128 x N] = A[128 x K] * B[N x K]^T  (R6 internals).
// A: bf16 row-major lda=K. B: fp32 weights [N][K]. C: bf16+relu or fp32.
// LDS tiles [128][64] bf16, 16B chunks XOR-swizzled: chunk c at c^((row>>1)&7).
template<int N, int K, bool RELU_OUT_BF16>
__device__ __forceinline__
void gemm_tile(const unsigned short* __restrict__ Ab, const float* __restrict__ Bp,
               void* __restrict__ Cp, int e, int nt, int tid,
               unsigned short (*sA)[128][64], unsigned short (*sB)[128][64])
{
    constexpr int BK = 64;
    constexpr int NT = K / BK;      // 16 (pass1) / 64 (pass2); even

    const int lane = tid & 63;
    const int w    = tid >> 6;
    const int wr   = w >> 1;
    const int wc   = w & 1;
    const int lrow = lane & 15;
    const int kq   = lane >> 4;

    const int arow = tid >> 3;       // 0..31
    const int ac   = tid & 7;        // chunk id 0..7
    const int swz  = (arow >> 1) & 7;

    const unsigned short* aBase = Ab + (size_t)(e * TOKS + arow) * K + ac * 8;
    const float*          bBase = Bp + ((size_t)e * N + (size_t)nt * 128 + arow) * K + ac * 8;

    const int sl = (lrow >> 1) & 7;
    const int offk0 = ((kq + 0) ^ sl) * 8;
    const int offk1 = ((kq + 4) ^ sl) * 8;

    f32x4 acc[4][4];
    #pragma unroll
    for (int i = 0; i < 4; ++i)
        #pragma unroll
        for (int n = 0; n < 4; ++n)
            #pragma unroll
            for (int q = 0; q < 4; ++q) acc[i][n][q] = 0.f;

    struct Regs {
        u32x4 a[4];
        f32x4 b[8];
    };
    Regs r0, r1;

    auto LOAD = [&](int t, Regs& r) {
        #pragma unroll
        for (int j = 0; j < 4; ++j)
            r.a[j] = *(const u32x4*)(aBase + (size_t)j * 32 * K + t * BK);
        #pragma unroll
        for (int j = 0; j < 4; ++j) {
            const f32x4* p = (const f32x4*)(bBase + (size_t)j * 32 * K + t * BK);
            r.b[2 * j]     = __builtin_nontemporal_load(p);
            r.b[2 * j + 1] = __builtin_nontemporal_load(p + 1);
        }
    };

    auto WRITE = [&](int buf, Regs& r) {
        const int c8 = (ac ^ swz) * 8;
        #pragma unroll
        for (int j = 0; j < 4; ++j)
            *(u32x4*)&sA[buf][arow + j * 32][c8] = r.a[j];
        #pragma unroll
        for (int j = 0; j < 4; ++j) {
            f32x4 lo = r.b[2 * j], hi = r.b[2 * j + 1];
            u32x4 u = { pack2(lo[0], lo[1]), pack2(lo[2], lo[3]),
                        pack2(hi[0], hi[1]), pack2(hi[2], hi[3]) };
            *(u32x4*)&sB[buf][arow + j * 32][c8] = u;
        }
    };

    auto COMPUTE = [&](int buf) {
        #pragma unroll
        for (int kh = 0; kh < 2; ++kh) {
            const int off = kh ? offk1 : offk0;
            bf16x8 af[4], bfr[4];
            #pragma unroll
            for (int i = 0; i < 4; ++i)
                af[i] = *(const bf16x8*)&sA[buf][wr * 64 + i * 16 + lrow][off];
            #pragma unroll
            for (int n = 0; n < 4; ++n)
                bfr[n] = *(const bf16x8*)&sB[buf][wc * 64 + n * 16 + lrow][off];
            #pragma unroll
            for (int i = 0; i < 4; ++i)
                #pragma unroll
                for (int n = 0; n < 4; ++n)
                    acc[i][n] = __builtin_amdgcn_mfma_f32_16x16x32_bf16(af[i], bfr[n], acc[i][n], 0, 0, 0);
        }
    };

    LOAD(0, r0);
    LOAD(1, r1);
    WRITE(0, r0);
    asm volatile("s_waitcnt lgkmcnt(0)" ::: "memory");
    __builtin_amdgcn_s_barrier();

    for (int t = 0; t < NT; t += 2) {
        if (t + 2 < NT) LOAD(t + 2, r0);
        COMPUTE(0);
        if (t + 1 < NT) WRITE(1, r1);
        asm volatile("s_waitcnt lgkmcnt(0)" ::: "memory");
        __builtin_amdgcn_s_barrier();

        if (t + 3 < NT) LOAD(t + 3, r1);
        COMPUTE(1);
        if (t + 2 < NT) WRITE(0, r0);
        asm volatile("s_waitcnt lgkmcnt(0)" ::: "memory");
        __builtin_amdgcn_s_barrier();
    }

    // Epilogue. C/D layout (m89-verified): col = lane&15, row = (lane>>4)*4 + reg
    const size_t crow0 = (size_t)e * TOKS;
    if constexpr (RELU_OUT_BF16) {
        unsigned short* C = (unsigned short*)Cp;
        #pragma unroll
        for (int i = 0; i < 4; ++i)
            #pragma unroll
            for (int n = 0; n < 4; ++n)
                #pragma unroll
                for (int q = 0; q < 4; ++q) {
                    const int row = wr * 64 + i * 16 + kq * 4 + q;
                    const int col = nt * 128 + wc * 64 + n * 16 + lrow;
                    C[(crow0 + row) * N + col] = f2bf(fmaxf(acc[i][n][q], 0.f));
                }
    } else {
        float* C = (float*)Cp;
        #pragma unroll
        for (int i = 0; i < 4; ++i)
            #pragma unroll
            for (int n = 0; n < 4; ++n)
                #pragma unroll
                for (int q = 0; q < 4; ++q) {
                    const int row = wr * 64 + i * 16 + kq * 4 + q;
                    const int col = nt * 128 + wc * 64 + n * 16 + lrow;
                    C[(crow0 + row) * N + col] = acc[i][n][q];
                }
    }
}

// Persistent fused kernel: blocks [0,2048) = pass1 tiles, [2048,2560) = pass2.
__global__ __launch_bounds__(256, 2)
void moe_fused(const unsigned short* __restrict__ xb, const float* __restrict__ w1,
               const float* __restrict__ w2, unsigned short* __restrict__ h,
               float* __restrict__ out, int* __restrict__ cnt)
{
    __shared__ unsigned short sA[2][128][64];
    __shared__ unsigned short sB[2][128][64];

    const int tid  = threadIdx.x;
    const int slot = blockIdx.x;

    if (slot < 2048) {
        // pass1: h[e] tile nt (0..31). XCD swizzle: nwg/xcd = 256.
        const int wid = (slot & 7) * 256 + (slot >> 3);
        const int e   = wid >> 5;         // /32
        const int nt  = wid & 31;
        gemm_tile<DH, DM, true>(xb, w1, (void*)h, e, nt, tid, sA, sB);
        __syncthreads();                   // drains all waves' stores (vmcnt 0)
        if (tid == 0) {
            __threadfence();               // agent-scope release (L2 writeback)
            __hip_atomic_fetch_add(&cnt[e], 1, __ATOMIC_RELEASE,
                                   __HIP_MEMORY_SCOPE_AGENT);
        }
    } else {
        // pass2: out[e] tile nt (0..7). XCD swizzle over 512: nwg/xcd = 64.
        const int s2  = slot - 2048;
        const int wid = (s2 & 7) * 64 + (s2 >> 3);
        const int e   = wid >> 3;          // /8
        const int nt  = wid & 7;
        if (tid == 0) {
            while (__hip_atomic_load(&cnt[e], __ATOMIC_ACQUIRE,
                                     __HIP_MEMORY_SCOPE_AGENT) < 32)
                __builtin_amdgcn_s_sleep(2);
        }
        __syncthreads();
        gemm_tile<DM, DH, false>(h, w2, (void*)out, e, nt, tid, sA, sB);
    }
}

extern "C" void kernel_launch(void* const* d_in, const int* in_sizes, int n_in,
                              void* d_out, int out_size, void* d_ws, size_t ws_size,
                              hipStream_t stream) {
    const float* inputs = (const float*)d_in[0];   // [8192, 1024] fp32
    const float* w1     = (const float*)d_in[1];   // [64, 4096, 1024] fp32
    const float* w2     = (const float*)d_in[2];   // [64, 1024, 4096] fp32
    // d_in[3] = splits (always 128) -- unused

    unsigned short* h  = (unsigned short*)d_ws;                                     // 64 MiB
    unsigned short* xb = (unsigned short*)((char*)d_ws + (size_t)64 * 1024 * 1024); // 16 MiB
    int* cnt = (int*)((char*)d_ws + (size_t)80 * 1024 * 1024);                      // 256 B
    float* out = (float*)d_out;

    // Pre-pass: x fp32 -> bf16, and zero the gate counters (every launch).
    const int n8 = (TOKS * N_EXPERTS) * DM / 8;    // 1,048,576
    cvt_bf16<<<dim3(n8 / 256), dim3(256), 0, stream>>>(inputs, (unsigned*)xb, n8, cnt);

    // Fused persistent pass1+pass2.
    moe_fused<<<dim3(2048 + 512), dim3(256), 0, stream>>>(xb, w1, w2, h, out, cnt);
}

// Round 10
// 645.919 us; speedup vs baseline: 1.0739x; 1.0739x over previous
//
#include <hip/hip_runtime.h>
#include <hip/hip_bf16.h>

// SeqExperts: 64 experts, 128 tokens each, d_model=1024, d_hidden=4096.
// out[e*128+m] = relu(x_e @ W1[e]^T) @ W2[e]^T
// R3 (540): counted-vmcnt double-buffer, XCD swizzle, BK=32, 128x128 tile.
// R4 (794 FAIL) no-LDS. R5 (707 FAIL) broken coalescing.
// R6 (521, BEST): BK=64 + chunk-XOR swizzle + pack2 + nontemporal W + x->bf16 prepass.
// R7 (529): depth-3 flat. R8 (622 FAIL): 128x64 tile. R9 (694 FAIL): fused
//     persistent + atomic gating (threadfence/L2-writeback per tile killed it).
// R10: R6 split structure, but SINGLE-buffered LDS (32 KB/block) ->
//      __launch_bounds__(256,4) -> 4 blocks/CU: 2x request streams + inter-block
//      TLP covers barriers. One reg-set (lower VGPR than R6's two-set 124).

typedef __attribute__((ext_vector_type(8))) short bf16x8;   // 8 bf16 (4 VGPRs)
typedef __attribute__((ext_vector_type(4))) float f32x4;
typedef __attribute__((ext_vector_type(4))) unsigned int u32x4;

#define N_EXPERTS 64
#define DM 1024
#define DH 4096
#define TOKS 128

__device__ __forceinline__ unsigned f2u(float f) {
    union { float f; unsigned u; } v; v.f = f; return v.u;
}
// round-half-up fp32->bf16 (0.5 ulp; no NaN/inf in data)
__device__ __forceinline__ unsigned short f2bf(float f) {
    return (unsigned short)((f2u(f) + 0x8000u) >> 16);
}
// pack two fp32 -> 2xbf16 in one u32
__device__ __forceinline__ unsigned pack2(float lo, float hi) {
    return ((f2u(lo) + 0x8000u) >> 16) | ((f2u(hi) + 0x8000u) & 0xFFFF0000u);
}

// elementwise fp32 -> bf16 (8 elems/thread)
__global__ __launch_bounds__(256)
void cvt_bf16(const float* __restrict__ in, unsigned* __restrict__ outp, int n8) {
    int i = blockIdx.x * blockDim.x + threadIdx.x;
    if (i >= n8) return;
    const f32x4* p = (const f32x4*)in + (size_t)i * 2;
    f32x4 a = p[0], b = p[1];
    u32x4 o = { pack2(a[0], a[1]), pack2(a[2], a[3]),
                pack2(b[0], b[1]), pack2(b[2], b[3]) };
    *((u32x4*)outp + i) = o;
}

// C[128 x N] = A[128 x K] * B[N x K]^T for expert e.
// A: bf16 row-major lda=K. B: fp32 weights [N][K]. C: bf16+relu or fp32.
// LDS tiles [128][64] bf16 (single buffer), 16B chunks XOR-swizzled:
// chunk c stored at c^((row>>1)&7); read offset (kq{+4})^((lrow>>1)&7).
template<int N, int K, bool RELU_OUT_BF16>
__global__ __launch_bounds__(256, 4)
void moe_gemm(const unsigned short* __restrict__ Ab, const float* __restrict__ Bp,
              void* __restrict__ Cp, int nwg_per_xcd)
{
    constexpr int BK = 64;
    constexpr int NT = K / BK;      // 16 (pass1) / 64 (pass2)
    constexpr int NTILES = N / 128;

    __shared__ unsigned short sA[128][BK];  // 16 KiB
    __shared__ unsigned short sB[128][BK];  // 16 KiB

    const int tid = threadIdx.x;
    const int bid = (blockIdx.x & 7) * nwg_per_xcd + (blockIdx.x >> 3);
    const int e   = bid / NTILES;
    const int nt  = bid % NTILES;

    const int lane = tid & 63;
    const int w    = tid >> 6;       // wave 0..3
    const int wr   = w >> 1;
    const int wc   = w & 1;
    const int lrow = lane & 15;
    const int kq   = lane >> 4;      // 0..3

    // staging: arow = tid>>3 (0..31; rows +j*32), ac = tid&7 (16B chunk).
    // Per instruction: 8 lanes cover a row's full 128B (A) / 256B in pairs (B).
    const int arow = tid >> 3;
    const int ac   = tid & 7;
    const int swz  = (arow >> 1) & 7;    // +j*32 preserves (>>1)&7

    const unsigned short* aBase = Ab + (size_t)(e * TOKS + arow) * K + ac * 8;
    const float*          bBase = Bp + ((size_t)e * N + (size_t)nt * 128 + arow) * K + ac * 8;

    const int sl = (lrow >> 1) & 7;
    const int offk0 = ((kq + 0) ^ sl) * 8;
    const int offk1 = ((kq + 4) ^ sl) * 8;

    f32x4 acc[4][4];
    #pragma unroll
    for (int i = 0; i < 4; ++i)
        #pragma unroll
        for (int n = 0; n < 4; ++n)
            #pragma unroll
            for (int q = 0; q < 4; ++q) acc[i][n][q] = 0.f;

    struct Regs {
        u32x4 a[4];    // 4 x 16B bf16 chunks (rows j*32)
        f32x4 b[8];    // 4 rows x 2 float4
    };
    Regs r;

    auto LOAD = [&](int t) {
        #pragma unroll
        for (int j = 0; j < 4; ++j)
            r.a[j] = *(const u32x4*)(aBase + (size_t)j * 32 * K + t * BK);
        #pragma unroll
        for (int j = 0; j < 4; ++j) {
            const f32x4* p = (const f32x4*)(bBase + (size_t)j * 32 * K + t * BK);
            r.b[2 * j]     = __builtin_nontemporal_load(p);      // weights: read-once
            r.b[2 * j + 1] = __builtin_nontemporal_load(p + 1);
        }
    };

    auto WRITE = [&]() {
        const int c8 = (ac ^ swz) * 8;
        #pragma unroll
        for (int j = 0; j < 4; ++j)
            *(u32x4*)&sA[arow + j * 32][c8] = r.a[j];
        #pragma unroll
        for (int j = 0; j < 4; ++j) {
            f32x4 lo = r.b[2 * j], hi = r.b[2 * j + 1];
            u32x4 u = { pack2(lo[0], lo[1]), pack2(lo[2], lo[3]),
                        pack2(hi[0], hi[1]), pack2(hi[2], hi[3]) };
            *(u32x4*)&sB[arow + j * 32][c8] = u;
        }
    };

    auto COMPUTE = [&]() {
        #pragma unroll
        for (int kh = 0; kh < 2; ++kh) {
            const int off = kh ? offk1 : offk0;
            bf16x8 af[4], bfr[4];
            #pragma unroll
            for (int i = 0; i < 4; ++i)
                af[i] = *(const bf16x8*)&sA[wr * 64 + i * 16 + lrow][off];
            #pragma unroll
            for (int n = 0; n < 4; ++n)
                bfr[n] = *(const bf16x8*)&sB[wc * 64 + n * 16 + lrow][off];
            #pragma unroll
            for (int i = 0; i < 4; ++i)
                #pragma unroll
                for (int n = 0; n < 4; ++n)
                    acc[i][n] = __builtin_amdgcn_mfma_f32_16x16x32_bf16(af[i], bfr[n], acc[i][n], 0, 0, 0);
        }
    };

    // Prologue
    LOAD(0);
    WRITE();
    asm volatile("s_waitcnt lgkmcnt(0)" ::: "memory");
    __builtin_amdgcn_s_barrier();

    for (int t = 0; t < NT; ++t) {
        if (t + 1 < NT) LOAD(t + 1);           // prefetch while computing t
        COMPUTE();
        __builtin_amdgcn_s_barrier();          // all reads of tile t done
        if (t + 1 < NT) {
            WRITE();                            // counted vmcnt waits only r's loads
            asm volatile("s_waitcnt lgkmcnt(0)" ::: "memory");
            __builtin_amdgcn_s_barrier();       // tile t+1 visible to all
        }
    }

    // Epilogue. C/D layout (m89-verified): col = lane&15, row = (lane>>4)*4 + reg
    const size_t crow0 = (size_t)e * TOKS;
    if constexpr (RELU_OUT_BF16) {
        unsigned short* C = (unsigned short*)Cp;
        #pragma unroll
        for (int i = 0; i < 4; ++i)
            #pragma unroll
            for (int n = 0; n < 4; ++n)
                #pragma unroll
                for (int q = 0; q < 4; ++q) {
                    const int row = wr * 64 + i * 16 + kq * 4 + q;
                    const int col = nt * 128 + wc * 64 + n * 16 + lrow;
                    C[(crow0 + row) * N + col] = f2bf(fmaxf(acc[i][n][q], 0.f));
                }
    } else {
        float* C = (float*)Cp;
        #pragma unroll
        for (int i = 0; i < 4; ++i)
            #pragma unroll
            for (int n = 0; n < 4; ++n)
                #pragma unroll
                for (int q = 0; q < 4; ++q) {
                    const int row = wr * 64 + i * 16 + kq * 4 + q;
                    const int col = nt * 128 + wc * 64 + n * 16 + lrow;
                    C[(crow0 + row) * N + col] = acc[i][n][q];
                }
    }
}

extern "C" void kernel_launch(void* const* d_in, const int* in_sizes, int n_in,
                              void* d_out, int out_size, void* d_ws, size_t ws_size,
                              hipStream_t stream) {
    const float* inputs = (const float*)d_in[0];   // [8192, 1024] fp32
    const float* w1     = (const float*)d_in[1];   // [64, 4096, 1024] fp32
    const float* w2     = (const float*)d_in[2];   // [64, 1024, 4096] fp32
    // d_in[3] = splits (always 128) -- unused

    unsigned short* h  = (unsigned short*)d_ws;                                     // 64 MiB
    unsigned short* xb = (unsigned short*)((char*)d_ws + (size_t)64 * 1024 * 1024); // 16 MiB
    float* out = (float*)d_out;

    // Pre-pass: x fp32 -> bf16
    const int n8 = (TOKS * N_EXPERTS) * DM / 8;    // 1,048,576
    cvt_bf16<<<dim3(n8 / 256), dim3(256), 0, stream>>>(inputs, (unsigned*)xb, n8);

    // Pass 1: h = relu(x @ w1^T), bf16. grid = 64*32 = 2048
    moe_gemm<DH, DM, true><<<dim3(N_EXPERTS * (DH / 128)), dim3(256), 0, stream>>>(
        xb, w1, h, N_EXPERTS * (DH / 128) / 8);
    // Pass 2: out = h @ w2^T, fp32. grid = 64*8 = 512
    moe_gemm<DM, DH, false><<<dim3(N_EXPERTS * (DM / 128)), dim3(256), 0, stream>>>(
        h, w2, out, N_EXPERTS * (DM / 128) / 8);
}

// Round 11
// 525.945 us; speedup vs baseline: 1.3189x; 1.2281x over previous
//
#include <hip/hip_runtime.h>
#include <hip/hip_bf16.h>

// SeqExperts: 64 experts, 128 tokens each, d_model=1024, d_hidden=4096.
// out[e*128+m] = relu(x_e @ W1[e]^T) @ W2[e]^T
// R3 (540): counted-vmcnt double-buffer, XCD swizzle, BK=32, 128x128 tile.
// R4 (794 FAIL) no-LDS. R5 (707 FAIL) broken coalescing.
// R6 (521, BEST): BK=64 + chunk-XOR swizzle + pack2 + nontemporal W + x->bf16 prepass.
// R7 (529) depth-3 flat. R8 (622 FAIL) 128x64 tile. R9 (694 FAIL) fused+gating.
// R10 (646 FAIL) single-buffer 4blk/CU (extra barrier drain).
// R11: CLEAN occupancy test: identical tile/pipeline/staging to R6 but
//      512-thread blocks (8 waves, wave-tile 64x32). LDS still 64 KB ->
//      2 blocks/CU -> 16 waves/CU (vs 8). Per-thread staging halves ->
//      VGPR ~116 <= 128 cap (__launch_bounds__(512,4)).

typedef __attribute__((ext_vector_type(8))) short bf16x8;   // 8 bf16 (4 VGPRs)
typedef __attribute__((ext_vector_type(4))) float f32x4;
typedef __attribute__((ext_vector_type(4))) unsigned int u32x4;

#define N_EXPERTS 64
#define DM 1024
#define DH 4096
#define TOKS 128

__device__ __forceinline__ unsigned f2u(float f) {
    union { float f; unsigned u; } v; v.f = f; return v.u;
}
// round-half-up fp32->bf16 (0.5 ulp; no NaN/inf in data)
__device__ __forceinline__ unsigned short f2bf(float f) {
    return (unsigned short)((f2u(f) + 0x8000u) >> 16);
}
// pack two fp32 -> 2xbf16 in one u32
__device__ __forceinline__ unsigned pack2(float lo, float hi) {
    return ((f2u(lo) + 0x8000u) >> 16) | ((f2u(hi) + 0x8000u) & 0xFFFF0000u);
}

// elementwise fp32 -> bf16 (8 elems/thread)
__global__ __launch_bounds__(256)
void cvt_bf16(const float* __restrict__ in, unsigned* __restrict__ outp, int n8) {
    int i = blockIdx.x * blockDim.x + threadIdx.x;
    if (i >= n8) return;
    const f32x4* p = (const f32x4*)in + (size_t)i * 2;
    f32x4 a = p[0], b = p[1];
    u32x4 o = { pack2(a[0], a[1]), pack2(a[2], a[3]),
                pack2(b[0], b[1]), pack2(b[2], b[3]) };
    *((u32x4*)outp + i) = o;
}

// C[128 x N] = A[128 x K] * B[N x K]^T for expert e. 512 threads / 8 waves.
// A: bf16 row-major lda=K. B: fp32 weights [N][K]. C: bf16+relu or fp32.
// LDS tiles [128][64] bf16 double-buffered; 16B chunks XOR-swizzled:
// chunk c stored at c^((row>>1)&7); read offset (kq{+4})^((lrow>>1)&7).
template<int N, int K, bool RELU_OUT_BF16>
__global__ __launch_bounds__(512, 4)
void moe_gemm(const unsigned short* __restrict__ Ab, const float* __restrict__ Bp,
              void* __restrict__ Cp, int nwg_per_xcd)
{
    constexpr int BK = 64;
    constexpr int NT = K / BK;      // 16 (pass1) / 64 (pass2); even
    constexpr int NTILES = N / 128;

    __shared__ unsigned short sA[2][128][BK];  // 16 KiB per buf
    __shared__ unsigned short sB[2][128][BK];

    const int tid = threadIdx.x;
    const int bid = (blockIdx.x & 7) * nwg_per_xcd + (blockIdx.x >> 3);
    const int e   = bid / NTILES;
    const int nt  = bid % NTILES;

    const int lane = tid & 63;
    const int w    = tid >> 6;       // wave 0..7
    const int wr   = w >> 2;         // row half (0..1): rows wr*64..+63
    const int wc   = w & 3;          // col quarter (0..3): cols wc*32..+31
    const int lrow = lane & 15;
    const int kq   = lane >> 4;      // 0..3

    // ---- staging (512 threads): arow = tid>>3 (0..63; rows +j*64), ac = tid&7.
    //      Per instruction: 8 lanes cover a row's 128B (A) / 32B-strided pair (B),
    //      8 rows per instruction -- same idiom as R6.
    const int arow = tid >> 3;
    const int ac   = tid & 7;
    const int swz  = (arow >> 1) & 7;    // +j*64 preserves (>>1)&7

    const unsigned short* aBase = Ab + (size_t)(e * TOKS + arow) * K + ac * 8;
    const float*          bBase = Bp + ((size_t)e * N + (size_t)nt * 128 + arow) * K + ac * 8;

    const int sl = (lrow >> 1) & 7;
    const int offk0 = ((kq + 0) ^ sl) * 8;
    const int offk1 = ((kq + 4) ^ sl) * 8;

    f32x4 acc[4][2];
    #pragma unroll
    for (int i = 0; i < 4; ++i)
        #pragma unroll
        for (int n = 0; n < 2; ++n)
            #pragma unroll
            for (int q = 0; q < 4; ++q) acc[i][n][q] = 0.f;

    struct Regs {
        u32x4 a[2];    // rows arow, arow+64 (16B chunk each)
        f32x4 b[4];    // 2 rows x 2 float4 (32B contiguous per row)
    };
    Regs r0, r1;

    auto LOAD = [&](int t, Regs& r) {
        #pragma unroll
        for (int j = 0; j < 2; ++j)
            r.a[j] = *(const u32x4*)(aBase + (size_t)j * 64 * K + t * BK);
        #pragma unroll
        for (int j = 0; j < 2; ++j) {
            const f32x4* p = (const f32x4*)(bBase + (size_t)j * 64 * K + t * BK);
            r.b[2 * j]     = __builtin_nontemporal_load(p);      // weights: read-once
            r.b[2 * j + 1] = __builtin_nontemporal_load(p + 1);
        }
    };

    auto WRITE = [&](int buf, Regs& r) {
        const int c8 = (ac ^ swz) * 8;
        #pragma unroll
        for (int j = 0; j < 2; ++j)
            *(u32x4*)&sA[buf][arow + j * 64][c8] = r.a[j];
        #pragma unroll
        for (int j = 0; j < 2; ++j) {
            f32x4 lo = r.b[2 * j], hi = r.b[2 * j + 1];
            u32x4 u = { pack2(lo[0], lo[1]), pack2(lo[2], lo[3]),
                        pack2(hi[0], hi[1]), pack2(hi[2], hi[3]) };
            *(u32x4*)&sB[buf][arow + j * 64][c8] = u;
        }
    };

    auto COMPUTE = [&](int buf) {
        #pragma unroll
        for (int kh = 0; kh < 2; ++kh) {
            const int off = kh ? offk1 : offk0;
            bf16x8 af[4], bfr[2];
            #pragma unroll
            for (int i = 0; i < 4; ++i)
                af[i] = *(const bf16x8*)&sA[buf][wr * 64 + i * 16 + lrow][off];
            #pragma unroll
            for (int n = 0; n < 2; ++n)
                bfr[n] = *(const bf16x8*)&sB[buf][wc * 32 + n * 16 + lrow][off];
            #pragma unroll
            for (int i = 0; i < 4; ++i)
                #pragma unroll
                for (int n = 0; n < 2; ++n)
                    acc[i][n] = __builtin_amdgcn_mfma_f32_16x16x32_bf16(af[i], bfr[n], acc[i][n], 0, 0, 0);
        }
    };

    // Prologue: 2 tiles in flight.
    LOAD(0, r0);
    LOAD(1, r1);
    WRITE(0, r0);                          // counted vmcnt: waits only set 0
    asm volatile("s_waitcnt lgkmcnt(0)" ::: "memory");
    __builtin_amdgcn_s_barrier();

    for (int t = 0; t < NT; t += 2) {
        if (t + 2 < NT) LOAD(t + 2, r0);
        COMPUTE(0);
        if (t + 1 < NT) WRITE(1, r1);      // r0's newer loads stay in flight
        asm volatile("s_waitcnt lgkmcnt(0)" ::: "memory");
        __builtin_amdgcn_s_barrier();

        if (t + 3 < NT) LOAD(t + 3, r1);
        COMPUTE(1);
        if (t + 2 < NT) WRITE(0, r0);
        asm volatile("s_waitcnt lgkmcnt(0)" ::: "memory");
        __builtin_amdgcn_s_barrier();
    }

    // Epilogue. C/D layout (m89-verified): col = lane&15, row = (lane>>4)*4 + reg
    const size_t crow0 = (size_t)e * TOKS;
    if constexpr (RELU_OUT_BF16) {
        unsigned short* C = (unsigned short*)Cp;
        #pragma unroll
        for (int i = 0; i < 4; ++i)
            #pragma unroll
            for (int n = 0; n < 2; ++n)
                #pragma unroll
                for (int q = 0; q < 4; ++q) {
                    const int row = wr * 64 + i * 16 + kq * 4 + q;
                    const int col = nt * 128 + wc * 32 + n * 16 + lrow;
                    C[(crow0 + row) * N + col] = f2bf(fmaxf(acc[i][n][q], 0.f));
                }
    } else {
        float* C = (float*)Cp;
        #pragma unroll
        for (int i = 0; i < 4; ++i)
            #pragma unroll
            for (int n = 0; n < 2; ++n)
                #pragma unroll
                for (int q = 0; q < 4; ++q) {
                    const int row = wr * 64 + i * 16 + kq * 4 + q;
                    const int col = nt * 128 + wc * 32 + n * 16 + lrow;
                    C[(crow0 + row) * N + col] = acc[i][n][q];
                }
    }
}

extern "C" void kernel_launch(void* const* d_in, const int* in_sizes, int n_in,
                              void* d_out, int out_size, void* d_ws, size_t ws_size,
                              hipStream_t stream) {
    const float* inputs = (const float*)d_in[0];   // [8192, 1024] fp32
    const float* w1     = (const float*)d_in[1];   // [64, 4096, 1024] fp32
    const float* w2     = (const float*)d_in[2];   // [64, 1024, 4096] fp32
    // d_in[3] = splits (always 128) -- unused

    unsigned short* h  = (unsigned short*)d_ws;                                     // 64 MiB
    unsigned short* xb = (unsigned short*)((char*)d_ws + (size_t)64 * 1024 * 1024); // 16 MiB
    float* out = (float*)d_out;

    // Pre-pass: x fp32 -> bf16
    const int n8 = (TOKS * N_EXPERTS) * DM / 8;    // 1,048,576
    cvt_bf16<<<dim3(n8 / 256), dim3(256), 0, stream>>>(inputs, (unsigned*)xb, n8);

    // Pass 1: h = relu(x @ w1^T), bf16. grid = 64*32 = 2048, 512 threads
    moe_gemm<DH, DM, true><<<dim3(N_EXPERTS * (DH / 128)), dim3(512), 0, stream>>>(
        xb, w1, h, N_EXPERTS * (DH / 128) / 8);
    // Pass 2: out = h @ w2^T, fp32. grid = 64*8 = 512, 512 threads
    moe_gemm<DM, DH, false><<<dim3(N_EXPERTS * (DM / 128)), dim3(512), 0, stream>>>(
        h, w2, out, N_EXPERTS * (DM / 128) / 8);
}

// Round 12
// 478.799 us; speedup vs baseline: 1.4487x; 1.0985x over previous
//
#include <hip/hip_runtime.h>
#include <hip/hip_bf16.h>

// SeqExperts: 64 experts, 128 tokens each, d_model=1024, d_hidden=4096.
// out[e*128+m] = relu(x_e @ W1[e]^T) @ W2[e]^T
// R3 (540): counted-vmcnt double-buffer, XCD swizzle, BK=32, 128x128 tile.
// R4 (794 FAIL) no-LDS. R5 (707 FAIL) broken coalescing.
// R6 (521, BEST): BK=64 + chunk-XOR swizzle + pack2 + nontemporal W + x->bf16 prepass.
// R7 (529) depth-3 flat. R8 (622 FAIL) 128x64 tile. R9 (694 FAIL) fused+gating.
// R10 (646 FAIL) single-buffer. R11 (526) 512-thr 16 waves/CU flat.
// R12: R6 minus two never-isolated ingredients with plausible negative sign:
//      (a) drop nontemporal on weight loads (may hurt L2 sector buffering of
//          the dominant 2.15 GB stream); (b) drop the x->bf16 prepass dispatch
//      (stage x fp32->bf16 inline in pass-1 WRITE; x re-reads are L2-served
//      across each XCD's 32 blocks). Two dispatches total.

typedef __attribute__((ext_vector_type(8))) short bf16x8;   // 8 bf16 (4 VGPRs)
typedef __attribute__((ext_vector_type(4))) float f32x4;
typedef __attribute__((ext_vector_type(4))) unsigned int u32x4;

#define N_EXPERTS 64
#define DM 1024
#define DH 4096
#define TOKS 128

__device__ __forceinline__ unsigned f2u(float f) {
    union { float f; unsigned u; } v; v.f = f; return v.u;
}
// round-half-up fp32->bf16 (0.5 ulp; no NaN/inf in data)
__device__ __forceinline__ unsigned short f2bf(float f) {
    return (unsigned short)((f2u(f) + 0x8000u) >> 16);
}
// pack two fp32 -> 2xbf16 in one u32
__device__ __forceinline__ unsigned pack2(float lo, float hi) {
    return ((f2u(lo) + 0x8000u) >> 16) | ((f2u(hi) + 0x8000u) & 0xFFFF0000u);
}

// C[128 x N] = A[128 x K] * B[N x K]^T for expert e.
// A: fp32 (pass1 x) or bf16 (pass2 h), row-major lda=K. B: fp32 weights [N][K].
// C: bf16+relu (pass1) or fp32 (pass2).
// LDS tiles [128][64] bf16 double-buffered; 16B chunks XOR-swizzled:
// chunk c stored at c^((row>>1)&7); read offset (kq{+4})^((lrow>>1)&7).
template<int N, int K, bool A_BF16, bool RELU_OUT_BF16>
__global__ __launch_bounds__(256, 2)
void moe_gemm(const void* __restrict__ Ap, const float* __restrict__ Bp,
              void* __restrict__ Cp, int nwg_per_xcd)
{
    constexpr int BK = 64;
    constexpr int NT = K / BK;      // 16 (pass1) / 64 (pass2); even
    constexpr int NTILES = N / 128;

    __shared__ unsigned short sA[2][128][BK];  // 16 KiB per buf
    __shared__ unsigned short sB[2][128][BK];

    const int tid = threadIdx.x;
    const int bid = (blockIdx.x & 7) * nwg_per_xcd + (blockIdx.x >> 3);
    const int e   = bid / NTILES;
    const int nt  = bid % NTILES;

    const int lane = tid & 63;
    const int w    = tid >> 6;       // wave 0..3
    const int wr   = w >> 1;
    const int wc   = w & 1;
    const int lrow = lane & 15;
    const int kq   = lane >> 4;      // 0..3

    // staging: arow = tid>>3 (0..31; rows +j*32), ac = tid&7 (16B bf16 chunk).
    // Coalesced: 8 lanes cover a row's full 128B bf16 / 256B fp32 contiguously.
    const int arow = tid >> 3;
    const int ac   = tid & 7;
    const int swz  = (arow >> 1) & 7;    // +j*32 preserves (>>1)&7

    const unsigned short* aBaseH = nullptr;
    const float*          aBaseF = nullptr;
    if constexpr (A_BF16)
        aBaseH = (const unsigned short*)Ap + (size_t)(e * TOKS + arow) * K + ac * 8;
    else
        aBaseF = (const float*)Ap + (size_t)(e * TOKS + arow) * K + ac * 8;

    const float* bBase = Bp + ((size_t)e * N + (size_t)nt * 128 + arow) * K + ac * 8;

    const int sl = (lrow >> 1) & 7;
    const int offk0 = ((kq + 0) ^ sl) * 8;
    const int offk1 = ((kq + 4) ^ sl) * 8;

    f32x4 acc[4][4];
    #pragma unroll
    for (int i = 0; i < 4; ++i)
        #pragma unroll
        for (int n = 0; n < 4; ++n)
            #pragma unroll
            for (int q = 0; q < 4; ++q) acc[i][n][q] = 0.f;

    struct Regs {
        u32x4 ah[4];   // A bf16: 4 x 16B chunks (rows j*32)       [A_BF16]
        f32x4 af[8];   // A fp32: 4 rows x 2 float4                 [!A_BF16]
        f32x4 b[8];    // B fp32: 4 rows x 2 float4
    };
    Regs r0, r1;

    auto LOAD = [&](int t, Regs& r) {
        if constexpr (A_BF16) {
            #pragma unroll
            for (int j = 0; j < 4; ++j)
                r.ah[j] = *(const u32x4*)(aBaseH + (size_t)j * 32 * K + t * BK);
        } else {
            #pragma unroll
            for (int j = 0; j < 4; ++j) {
                const f32x4* p = (const f32x4*)(aBaseF + (size_t)j * 32 * K + t * BK);
                r.af[2 * j]     = p[0];
                r.af[2 * j + 1] = p[1];
            }
        }
        #pragma unroll
        for (int j = 0; j < 4; ++j) {
            const f32x4* p = (const f32x4*)(bBase + (size_t)j * 32 * K + t * BK);
            r.b[2 * j]     = p[0];
            r.b[2 * j + 1] = p[1];
        }
    };

    auto WRITE = [&](int buf, Regs& r) {
        const int c8 = (ac ^ swz) * 8;
        if constexpr (A_BF16) {
            #pragma unroll
            for (int j = 0; j < 4; ++j)
                *(u32x4*)&sA[buf][arow + j * 32][c8] = r.ah[j];
        } else {
            #pragma unroll
            for (int j = 0; j < 4; ++j) {
                f32x4 lo = r.af[2 * j], hi = r.af[2 * j + 1];
                u32x4 u = { pack2(lo[0], lo[1]), pack2(lo[2], lo[3]),
                            pack2(hi[0], hi[1]), pack2(hi[2], hi[3]) };
                *(u32x4*)&sA[buf][arow + j * 32][c8] = u;
            }
        }
        #pragma unroll
        for (int j = 0; j < 4; ++j) {
            f32x4 lo = r.b[2 * j], hi = r.b[2 * j + 1];
            u32x4 u = { pack2(lo[0], lo[1]), pack2(lo[2], lo[3]),
                        pack2(hi[0], hi[1]), pack2(hi[2], hi[3]) };
            *(u32x4*)&sB[buf][arow + j * 32][c8] = u;
        }
    };

    auto COMPUTE = [&](int buf) {
        #pragma unroll
        for (int kh = 0; kh < 2; ++kh) {
            const int off = kh ? offk1 : offk0;
            bf16x8 af[4], bfr[4];
            #pragma unroll
            for (int i = 0; i < 4; ++i)
                af[i] = *(const bf16x8*)&sA[buf][wr * 64 + i * 16 + lrow][off];
            #pragma unroll
            for (int n = 0; n < 4; ++n)
                bfr[n] = *(const bf16x8*)&sB[buf][wc * 64 + n * 16 + lrow][off];
            #pragma unroll
            for (int i = 0; i < 4; ++i)
                #pragma unroll
                for (int n = 0; n < 4; ++n)
                    acc[i][n] = __builtin_amdgcn_mfma_f32_16x16x32_bf16(af[i], bfr[n], acc[i][n], 0, 0, 0);
        }
    };

    // Prologue: 2 tiles in flight.
    LOAD(0, r0);
    LOAD(1, r1);
    WRITE(0, r0);                          // counted vmcnt: waits only set 0
    asm volatile("s_waitcnt lgkmcnt(0)" ::: "memory");
    __builtin_amdgcn_s_barrier();

    for (int t = 0; t < NT; t += 2) {
        if (t + 2 < NT) LOAD(t + 2, r0);
        COMPUTE(0);
        if (t + 1 < NT) WRITE(1, r1);      // r0's newer loads stay in flight
        asm volatile("s_waitcnt lgkmcnt(0)" ::: "memory");
        __builtin_amdgcn_s_barrier();

        if (t + 3 < NT) LOAD(t + 3, r1);
        COMPUTE(1);
        if (t + 2 < NT) WRITE(0, r0);
        asm volatile("s_waitcnt lgkmcnt(0)" ::: "memory");
        __builtin_amdgcn_s_barrier();
    }

    // Epilogue. C/D layout (m89-verified): col = lane&15, row = (lane>>4)*4 + reg
    const size_t crow0 = (size_t)e * TOKS;
    if constexpr (RELU_OUT_BF16) {
        unsigned short* C = (unsigned short*)Cp;
        #pragma unroll
        for (int i = 0; i < 4; ++i)
            #pragma unroll
            for (int n = 0; n < 4; ++n)
                #pragma unroll
                for (int q = 0; q < 4; ++q) {
                    const int row = wr * 64 + i * 16 + kq * 4 + q;
                    const int col = nt * 128 + wc * 64 + n * 16 + lrow;
                    C[(crow0 + row) * N + col] = f2bf(fmaxf(acc[i][n][q], 0.f));
                }
    } else {
        float* C = (float*)Cp;
        #pragma unroll
        for (int i = 0; i < 4; ++i)
            #pragma unroll
            for (int n = 0; n < 4; ++n)
                #pragma unroll
                for (int q = 0; q < 4; ++q) {
                    const int row = wr * 64 + i * 16 + kq * 4 + q;
                    const int col = nt * 128 + wc * 64 + n * 16 + lrow;
                    C[(crow0 + row) * N + col] = acc[i][n][q];
                }
    }
}

extern "C" void kernel_launch(void* const* d_in, const int* in_sizes, int n_in,
                              void* d_out, int out_size, void* d_ws, size_t ws_size,
                              hipStream_t stream) {
    const float* inputs = (const float*)d_in[0];   // [8192, 1024] fp32
    const float* w1     = (const float*)d_in[1];   // [64, 4096, 1024] fp32
    const float* w2     = (const float*)d_in[2];   // [64, 1024, 4096] fp32
    // d_in[3] = splits (always 128) -- unused

    unsigned short* h = (unsigned short*)d_ws;     // [8192, 4096] bf16 = 64 MiB
    float* out = (float*)d_out;                    // [8192, 1024] fp32

    // Pass 1: h = relu(x @ w1^T), bf16; x staged fp32->bf16 inline. grid = 2048
    moe_gemm<DH, DM, false, true><<<dim3(N_EXPERTS * (DH / 128)), dim3(256), 0, stream>>>(
        inputs, w1, h, N_EXPERTS * (DH / 128) / 8);
    // Pass 2: out = h @ w2^T, fp32. grid = 512
    moe_gemm<DM, DH, true, false><<<dim3(N_EXPERTS * (DM / 128)), dim3(256), 0, stream>>>(
        h, w2, out, N_EXPERTS * (DM / 128) / 8);
}